// Round 15
// baseline (111.571 us; speedup 1.0000x reference)
//
#include <hip/hip_runtime.h>
#include <hip/hip_bf16.h>
#include <stdint.h>

#define S_LEN 4096
#define DIM   512
#define NH    8
#define HD    64
#define NZ    4      // KV split factor
#define ZROWS 1024   // kv rows per chunk
// 0.125 * log2(e): fold softmax base-2 conversion into the Q projection weights
#define QSCALE 0.18033688011112042f

typedef __attribute__((ext_vector_type(8))) short short8;
typedef __attribute__((ext_vector_type(4))) float f32x4;
typedef __attribute__((ext_vector_type(16))) float f32x16;
typedef __attribute__((ext_vector_type(2))) unsigned uint2v;

__device__ __forceinline__ uint32_t pk2(float lo, float hi) {
  union { __hip_bfloat162 h; uint32_t u; } cv;
  cv.h = __float22bfloat162_rn(float2{lo, hi});
  return cv.u;
}
__device__ __forceinline__ ushort bf1(float x) {
  union { __hip_bfloat16 b; ushort u; } cv;
  cv.b = __float2bfloat16(x);
  return cv.u;
}
__device__ __forceinline__ float bf2f(ushort u) {
  union { uint32_t u; float f; } cv;
  cv.u = (uint32_t)u << 16;
  return cv.f;
}
// raw v_exp_f32: 2^x (args bounded by defer-max, no range fixup needed)
__device__ __forceinline__ float fexp2(float x) {
  float r;
  asm("v_exp_f32 %0, %1" : "=v"(r) : "v"(x));
  return r;
}

// ---------------- prep: x -> bf16 ----------------
__global__ __launch_bounds__(256)
void cast_x(const float* __restrict__ src, ushort* __restrict__ dst) {
  const int i = (blockIdx.x * 256 + threadIdx.x) * 8;
  const float4 a = *reinterpret_cast<const float4*>(src + i);
  const float4 b = *reinterpret_cast<const float4*>(src + i + 4);
  uint4 o;
  o.x = pk2(a.x, a.y); o.y = pk2(a.z, a.w);
  o.z = pk2(b.x, b.y); o.w = pk2(b.z, b.w);
  *reinterpret_cast<uint4*>(dst + i) = o;
}

// ---------------- prep: transpose weights to bf16 ----------------
__global__ __launch_bounds__(256)
void transpose_w(const float* __restrict__ qp, const float* __restrict__ kp,
                 const float* __restrict__ vp, const float* __restrict__ pp,
                 ushort* __restrict__ wbT, ushort* __restrict__ ppT) {
  __shared__ float L[64][65];
  const int z = blockIdx.z;
  const float* src = (z == 0) ? qp : (z == 1) ? kp : (z == 2) ? vp : pp;
  ushort* dst = (z < 3) ? (wbT + (size_t)z * 512 * 512) : ppT;
  const float scale = (z == 0) ? QSCALE : 1.0f;
  const int k0 = blockIdx.x * 64, n0 = blockIdx.y * 64;
  const int r = threadIdx.x >> 2, c0 = (threadIdx.x & 3) * 16;

#pragma unroll
  for (int j = 0; j < 4; ++j) {
    const float4 v =
        *reinterpret_cast<const float4*>(&src[(k0 + r) * 512 + n0 + c0 + 4 * j]);
    L[r][c0 + 4 * j + 0] = v.x * scale;
    L[r][c0 + 4 * j + 1] = v.y * scale;
    L[r][c0 + 4 * j + 2] = v.z * scale;
    L[r][c0 + 4 * j + 3] = v.w * scale;
  }
  __syncthreads();

  uint4 u0, u1;
  u0.x = pk2(L[c0 + 0][r], L[c0 + 1][r]);
  u0.y = pk2(L[c0 + 2][r], L[c0 + 3][r]);
  u0.z = pk2(L[c0 + 4][r], L[c0 + 5][r]);
  u0.w = pk2(L[c0 + 6][r], L[c0 + 7][r]);
  u1.x = pk2(L[c0 + 8][r], L[c0 + 9][r]);
  u1.y = pk2(L[c0 + 10][r], L[c0 + 11][r]);
  u1.z = pk2(L[c0 + 12][r], L[c0 + 13][r]);
  u1.w = pk2(L[c0 + 14][r], L[c0 + 15][r]);
  ushort* d = dst + (size_t)(n0 + r) * 512 + k0 + c0;
  *reinterpret_cast<uint4*>(d) = u0;
  *reinterpret_cast<uint4*>(d + 8) = u1;
}

// ---------------- bf16 MFMA GEMM (BM=128, BN=64, BK=64) ----------------
// MODE 0: qkv out (Q,K row-major planes; V plane transposed).
// MODE 1: f32 out.
// MODE 2: A = opart (4 partials merged inline with ML weights), f32 out.
template <int MODE>
__global__ __launch_bounds__(256)
void gemm_bf16(const ushort* __restrict__ A, const ushort* __restrict__ Bt,
               void* __restrict__ Cout, const float2* __restrict__ ML) {
  __shared__ __align__(16) unsigned char lds[24576];  // As 16K | Bs 8K
  const int tid = threadIdx.x;
  const int m0 = blockIdx.x * 128, n0 = blockIdx.y * 64;
  const int lane = tid & 63, w = tid >> 6;
  const int wm = w >> 1, wn = w & 1;
  const int q = lane & 15, g = lane >> 4;
  f32x4 acc[4][2] = {};

  const int ar = tid >> 1, ah = tid & 1;
  const int br = tid >> 2, bq = tid & 3;

  for (int k0 = 0; k0 < 512; k0 += 64) {
    uint4 a0, a1, a2, a3;
    if constexpr (MODE != 2) {
      const ushort* ag = A + (size_t)(m0 + ar) * 512 + k0 + ah * 32;
      a0 = *reinterpret_cast<const uint4*>(ag);
      a1 = *reinterpret_cast<const uint4*>(ag + 8);
      a2 = *reinterpret_cast<const uint4*>(ag + 16);
      a3 = *reinterpret_cast<const uint4*>(ag + 24);
    } else {
      // fused combine: A[srow][hd*64+d0..+31] = sum_z wz * opart[z*8+hd][srow][d]
      const int srow = m0 + ar;
      const int hd = k0 >> 6;
      const int d0 = ah * 32;
      float mz[4], lz[4];
      float mM = -1e30f;
#pragma unroll
      for (int z = 0; z < NZ; ++z) {
        const float2 v = ML[(size_t)(z * 8 + hd) * S_LEN + srow];
        mz[z] = v.x; lz[z] = v.y;
        mM = fmaxf(mM, v.x);
      }
      float wz[4], l = 0.f;
#pragma unroll
      for (int z = 0; z < NZ; ++z) {
        wz[z] = fexp2(mz[z] - mM);
        l += wz[z] * lz[z];
      }
      const float inv = 1.0f / l;
#pragma unroll
      for (int z = 0; z < NZ; ++z) wz[z] *= inv;

      float a[32];
#pragma unroll
      for (int j = 0; j < 32; ++j) a[j] = 0.f;
#pragma unroll
      for (int z = 0; z < NZ; ++z) {
        const ushort* src =
            A + ((size_t)(z * 8 + hd) * S_LEN + srow) * HD + d0;
        const uint4 u0 = *reinterpret_cast<const uint4*>(src);
        const uint4 u1 = *reinterpret_cast<const uint4*>(src + 8);
        const uint4 u2 = *reinterpret_cast<const uint4*>(src + 16);
        const uint4 u3 = *reinterpret_cast<const uint4*>(src + 24);
        const ushort* e0 = reinterpret_cast<const ushort*>(&u0);
        const ushort* e1 = reinterpret_cast<const ushort*>(&u1);
        const ushort* e2 = reinterpret_cast<const ushort*>(&u2);
        const ushort* e3 = reinterpret_cast<const ushort*>(&u3);
#pragma unroll
        for (int j = 0; j < 8; ++j) {
          a[j] = fmaf(wz[z], bf2f(e0[j]), a[j]);
          a[j + 8] = fmaf(wz[z], bf2f(e1[j]), a[j + 8]);
          a[j + 16] = fmaf(wz[z], bf2f(e2[j]), a[j + 16]);
          a[j + 24] = fmaf(wz[z], bf2f(e3[j]), a[j + 24]);
        }
      }
      uint4 pa[4];
#pragma unroll
      for (int g4 = 0; g4 < 4; ++g4) {
        pa[g4].x = pk2(a[8 * g4 + 0], a[8 * g4 + 1]);
        pa[g4].y = pk2(a[8 * g4 + 2], a[8 * g4 + 3]);
        pa[g4].z = pk2(a[8 * g4 + 4], a[8 * g4 + 5]);
        pa[g4].w = pk2(a[8 * g4 + 6], a[8 * g4 + 7]);
      }
      a0 = pa[0]; a1 = pa[1]; a2 = pa[2]; a3 = pa[3];
    }
    const ushort* bg = Bt + (size_t)(n0 + br) * 512 + k0 + bq * 16;
    const uint4 b0 = *reinterpret_cast<const uint4*>(bg);
    const uint4 b1 = *reinterpret_cast<const uint4*>(bg + 8);
    __syncthreads();
    {
      unsigned char* ab = lds + ar * 128;
      const int asw = (ar & 7) << 4;
      *reinterpret_cast<uint4*>(ab + ((ah * 64 + 0) ^ asw)) = a0;
      *reinterpret_cast<uint4*>(ab + ((ah * 64 + 16) ^ asw)) = a1;
      *reinterpret_cast<uint4*>(ab + ((ah * 64 + 32) ^ asw)) = a2;
      *reinterpret_cast<uint4*>(ab + ((ah * 64 + 48) ^ asw)) = a3;
      unsigned char* bb = lds + 16384 + br * 128;
      const int bsw = (br & 7) << 4;
      *reinterpret_cast<uint4*>(bb + ((bq * 32 + 0) ^ bsw)) = b0;
      *reinterpret_cast<uint4*>(bb + ((bq * 32 + 16) ^ bsw)) = b1;
    }
    __syncthreads();

#pragma unroll
    for (int ks = 0; ks < 2; ++ks) {
      short8 bf[2];
#pragma unroll
      for (int ni = 0; ni < 2; ++ni) {
        const int rn = wn * 32 + ni * 16 + q;
        bf[ni] = *reinterpret_cast<const short8*>(
            lds + 16384 + rn * 128 + ((64 * ks + 16 * g) ^ ((rn & 7) << 4)));
      }
#pragma unroll
      for (int mi = 0; mi < 4; ++mi) {
        const int rm = wm * 64 + mi * 16 + q;
        const short8 af = *reinterpret_cast<const short8*>(
            lds + rm * 128 + ((64 * ks + 16 * g) ^ ((rm & 7) << 4)));
#pragma unroll
        for (int ni = 0; ni < 2; ++ni)
          acc[mi][ni] = __builtin_amdgcn_mfma_f32_16x16x32_bf16(
              af, bf[ni], acc[mi][ni], 0, 0, 0);
      }
    }
  }

  if constexpr (MODE == 0) {
    ushort* C = (ushort*)Cout;
    const int which = n0 >> 9;
#pragma unroll
    for (int ni = 0; ni < 2; ++ni) {
      const int n = n0 + wn * 32 + ni * 16 + q;
      const int rem = n & 511, hh = rem >> 6, d = rem & 63;
      if (which == 2) {  // V transposed: [64 d][4096 s]
        ushort* base = C + (size_t)(2 * NH + hh) * (size_t)(S_LEN * HD) +
                       (size_t)d * S_LEN;
#pragma unroll
        for (int mi = 0; mi < 4; ++mi) {
          const int s = m0 + wm * 64 + mi * 16 + 4 * g;
          uint2 pw;
          pw.x = pk2(acc[mi][ni][0], acc[mi][ni][1]);
          pw.y = pk2(acc[mi][ni][2], acc[mi][ni][3]);
          *reinterpret_cast<uint2*>(base + s) = pw;
        }
      } else {
        ushort* base =
            C + ((size_t)which * NH + hh) * (size_t)(S_LEN * HD) + d;
#pragma unroll
        for (int mi = 0; mi < 4; ++mi) {
          const int s = m0 + wm * 64 + mi * 16 + 4 * g;
#pragma unroll
          for (int r = 0; r < 4; ++r)
            base[(size_t)(s + r) * HD] = bf1(acc[mi][ni][r]);
        }
      }
    }
  } else {
    float* C = (float*)Cout;
#pragma unroll
    for (int ni = 0; ni < 2; ++ni) {
      const int n = n0 + wn * 32 + ni * 16 + q;
#pragma unroll
      for (int mi = 0; mi < 4; ++mi) {
        const int s = m0 + wm * 64 + mi * 16 + 4 * g;
#pragma unroll
        for (int r = 0; r < 4; ++r)
          C[(size_t)(s + r) * 512 + n] = acc[mi][ni][r];
      }
    }
  }
}

// ------- MFMA flash attention: T15 PIPELINED (PV(t-1) overlaps SM(t)) -------
// R14 merged-softmax base; per iteration:
//   write(t) -> barrier -> [stage-issue t+1] QK(t) -> PV(t-1) -> SM(t)->pf(t)
// pf carried across iterations (32 VGPRs). K double-buffered, V TRIPLE-
// buffered (PV(t-1) reads V(t-1) one iteration late; barrier(t+1) separates
// those reads from the t+2 rewrite of that slot). One barrier per tile.
__global__ __launch_bounds__(256, 2)
void attn_mfma32(const ushort* __restrict__ QKV, ushort* __restrict__ Opart,
                 float2* __restrict__ ML) {
  __shared__ __align__(16) unsigned char lds[40960];  // K 2x8K | V 3x8K
  const int tid = threadIdx.x;
  const int combo = blockIdx.x;
  const int h = combo & 7, z = combo >> 3;
  const int qb = blockIdx.y;
  const int lane = tid & 63, w = tid >> 6;
  const int r31 = lane & 31, hh = lane >> 5;

  const size_t plane = (size_t)S_LEN * HD;
  const ushort* Qp = QKV + (size_t)h * plane;
  const ushort* Kp = QKV + (size_t)(NH + h) * plane;       // [4096][64]
  const ushort* Vp = QKV + (size_t)(2 * NH + h) * plane;   // [64][4096]

  const int qbase = qb * 256 + w * 64;
  const int qrowA = qbase + r31, qrowB = qbase + 32 + r31;

  short8 qfA[4], qfB[4];
  {
    const ushort* qa = Qp + (size_t)qrowA * HD + 8 * hh;
    const ushort* qbp = Qp + (size_t)qrowB * HD + 8 * hh;
#pragma unroll
    for (int ks = 0; ks < 4; ++ks) {
      qfA[ks] = *reinterpret_cast<const short8*>(qa + 16 * ks);
      qfB[ks] = *reinterpret_cast<const short8*>(qbp + 16 * ks);
    }
  }

  int roff[4];
#pragma unroll
  for (int ks = 0; ks < 4; ++ks)
    roff[ks] = (((2 * ks + hh) << 4) ^ ((r31 & 7) << 4));
  const int rbase = r31 * 128;

  const int trow = tid >> 2, seg = tid & 3;
  const int tsw = (trow & 7) << 4;
  const int wk0 = trow * 128 + ((seg * 32) ^ tsw);
  const int wk1 = trow * 128 + ((seg * 32 + 16) ^ tsw);
  const ushort* kgbase = Kp + (size_t)(z * ZROWS + trow) * HD + seg * 16;
  const ushort* vgbase = Vp + (size_t)trow * S_LEN + z * ZROWS + seg * 16;

  f32x16 oA[2] = {}, oB[2] = {};
  float mA = -1e30f, lA = 0.f, mB = -1e30f, lB = 0.f;
  short8 pfA[4], pfB[4];  // packed P, carried tile->tile

  // V fragment read offsets (within a V buffer)
  int vfoff[2][4];
#pragma unroll
  for (int dt = 0; dt < 2; ++dt)
#pragma unroll
    for (int kg = 0; kg < 4; ++kg)
      vfoff[dt][kg] = (32 * dt + r31) * 128 +
                      ((32 * kg + 16 * hh) ^ ((r31 & 7) << 4));

  // ---------------- prologue: tile 0 ----------------
  uint4 kst0 = *reinterpret_cast<const uint4*>(kgbase);
  uint4 kst1 = *reinterpret_cast<const uint4*>(kgbase + 8);
  uint4 vst0 = *reinterpret_cast<const uint4*>(vgbase);
  uint4 vst1 = *reinterpret_cast<const uint4*>(vgbase + 8);

  int kpoW = 0;      // K slot: 0 / 8192
  int vW = 16384;    // V slot: 16384 / 24576 / 32768
  int vR = 16384;

  f32x16 sA0, sA1, sB0, sB1;

  // macro-ish lambdas keep the proven R14 blocks verbatim
  auto do_qk = [&](int kpo) {
    sA0 = f32x16{}; sA1 = f32x16{}; sB0 = f32x16{}; sB1 = f32x16{};
    __builtin_amdgcn_s_setprio(1);
#pragma unroll
    for (int ks = 0; ks < 4; ++ks) {
      const short8 af0 =
          *reinterpret_cast<const short8*>(lds + kpo + rbase + roff[ks]);
      const short8 af1 =
          *reinterpret_cast<const short8*>(lds + kpo + 4096 + rbase + roff[ks]);
      sA0 = __builtin_amdgcn_mfma_f32_32x32x16_bf16(af0, qfA[ks], sA0, 0, 0, 0);
      sB0 = __builtin_amdgcn_mfma_f32_32x32x16_bf16(af0, qfB[ks], sB0, 0, 0, 0);
      sA1 = __builtin_amdgcn_mfma_f32_32x32x16_bf16(af1, qfA[ks], sA1, 0, 0, 0);
      sB1 = __builtin_amdgcn_mfma_f32_32x32x16_bf16(af1, qfB[ks], sB1, 0, 0, 0);
    }
    __builtin_amdgcn_s_setprio(0);
  };

  auto do_pv = [&](int vpo) {
    __builtin_amdgcn_s_setprio(1);
#pragma unroll
    for (int dt = 0; dt < 2; ++dt)
#pragma unroll
      for (int kg = 0; kg < 4; ++kg) {
        const short8 vf =
            *reinterpret_cast<const short8*>(lds + vpo + vfoff[dt][kg]);
        oA[dt] = __builtin_amdgcn_mfma_f32_32x32x16_bf16(vf, pfA[kg], oA[dt],
                                                         0, 0, 0);
        oB[dt] = __builtin_amdgcn_mfma_f32_32x32x16_bf16(vf, pfB[kg], oB[dt],
                                                         0, 0, 0);
      }
    __builtin_amdgcn_s_setprio(0);
  };

  auto do_sm_pack = [&]() {
    {
      float mv[8];
#pragma unroll
      for (int i = 0; i < 8; ++i)
        mv[i] = fmaxf(fmaxf(sA0[i], sA0[i + 8]), fmaxf(sA1[i], sA1[i + 8]));
#pragma unroll
      for (int i = 0; i < 4; ++i) mv[i] = fmaxf(mv[i], mv[i + 4]);
      float mx = fmaxf(fmaxf(mv[0], mv[1]), fmaxf(mv[2], mv[3]));
      mx = fmaxf(mx, __shfl_xor(mx, 32));
      const bool grow = mx > mA + 8.0f;
      if (__any(grow)) {
        const float mn = grow ? mx : mA;
        const float alpha = grow ? fexp2(mA - mn) : 1.0f;
        lA *= alpha;
#pragma unroll
        for (int i = 0; i < 16; ++i) { oA[0][i] *= alpha; oA[1][i] *= alpha; }
        mA = mn;
      }
      float r0 = 0.f, r1 = 0.f, r2 = 0.f, r3 = 0.f;
#pragma unroll
      for (int i = 0; i < 16; i += 4) {
        sA0[i + 0] = fexp2(sA0[i + 0] - mA); r0 += sA0[i + 0];
        sA0[i + 1] = fexp2(sA0[i + 1] - mA); r1 += sA0[i + 1];
        sA0[i + 2] = fexp2(sA0[i + 2] - mA); r2 += sA0[i + 2];
        sA0[i + 3] = fexp2(sA0[i + 3] - mA); r3 += sA0[i + 3];
        sA1[i + 0] = fexp2(sA1[i + 0] - mA); r0 += sA1[i + 0];
        sA1[i + 1] = fexp2(sA1[i + 1] - mA); r1 += sA1[i + 1];
        sA1[i + 2] = fexp2(sA1[i + 2] - mA); r2 += sA1[i + 2];
        sA1[i + 3] = fexp2(sA1[i + 3] - mA); r3 += sA1[i + 3];
      }
      lA += (r0 + r1) + (r2 + r3);
    }
    {
      float mv[8];
#pragma unroll
      for (int i = 0; i < 8; ++i)
        mv[i] = fmaxf(fmaxf(sB0[i], sB0[i + 8]), fmaxf(sB1[i], sB1[i + 8]));
#pragma unroll
      for (int i = 0; i < 4; ++i) mv[i] = fmaxf(mv[i], mv[i + 4]);
      float mx = fmaxf(fmaxf(mv[0], mv[1]), fmaxf(mv[2], mv[3]));
      mx = fmaxf(mx, __shfl_xor(mx, 32));
      const bool grow = mx > mB + 8.0f;
      if (__any(grow)) {
        const float mn = grow ? mx : mB;
        const float alpha = grow ? fexp2(mB - mn) : 1.0f;
        lB *= alpha;
#pragma unroll
        for (int i = 0; i < 16; ++i) { oB[0][i] *= alpha; oB[1][i] *= alpha; }
        mB = mn;
      }
      float r0 = 0.f, r1 = 0.f, r2 = 0.f, r3 = 0.f;
#pragma unroll
      for (int i = 0; i < 16; i += 4) {
        sB0[i + 0] = fexp2(sB0[i + 0] - mB); r0 += sB0[i + 0];
        sB0[i + 1] = fexp2(sB0[i + 1] - mB); r1 += sB0[i + 1];
        sB0[i + 2] = fexp2(sB0[i + 2] - mB); r2 += sB0[i + 2];
        sB0[i + 3] = fexp2(sB0[i + 3] - mB); r3 += sB0[i + 3];
        sB1[i + 0] = fexp2(sB1[i + 0] - mB); r0 += sB1[i + 0];
        sB1[i + 1] = fexp2(sB1[i + 1] - mB); r1 += sB1[i + 1];
        sB1[i + 2] = fexp2(sB1[i + 2] - mB); r2 += sB1[i + 2];
        sB1[i + 3] = fexp2(sB1[i + 3] - mB); r3 += sB1[i + 3];
      }
      lB += (r0 + r1) + (r2 + r3);
    }
#pragma unroll
    for (int e = 0; e < 2; ++e) {
      const int bb = 2 * e;
      {
        const uint32_t u00 = pk2(sA0[4 * bb + 0], sA0[4 * bb + 1]);
        const uint32_t u01 = pk2(sA0[4 * bb + 2], sA0[4 * bb + 3]);
        const uint32_t u10 = pk2(sA0[4 * bb + 4], sA0[4 * bb + 5]);
        const uint32_t u11 = pk2(sA0[4 * bb + 6], sA0[4 * bb + 7]);
        const uint2v se0 =
            __builtin_amdgcn_permlane32_swap(u00, u10, false, false);
        const uint2v se1 =
            __builtin_amdgcn_permlane32_swap(u01, u11, false, false);
        uint32_t fr[4] = {se0.x, se1.x, se0.y, se1.y};
        pfA[e] = *reinterpret_cast<short8*>(fr);
      }
      {
        const uint32_t u00 = pk2(sA1[4 * bb + 0], sA1[4 * bb + 1]);
        const uint32_t u01 = pk2(sA1[4 * bb + 2], sA1[4 * bb + 3]);
        const uint32_t u10 = pk2(sA1[4 * bb + 4], sA1[4 * bb + 5]);
        const uint32_t u11 = pk2(sA1[4 * bb + 6], sA1[4 * bb + 7]);
        const uint2v se0 =
            __builtin_amdgcn_permlane32_swap(u00, u10, false, false);
        const uint2v se1 =
            __builtin_amdgcn_permlane32_swap(u01, u11, false, false);
        uint32_t fr[4] = {se0.x, se1.x, se0.y, se1.y};
        pfA[2 + e] = *reinterpret_cast<short8*>(fr);
      }
      {
        const uint32_t u00 = pk2(sB0[4 * bb + 0], sB0[4 * bb + 1]);
        const uint32_t u01 = pk2(sB0[4 * bb + 2], sB0[4 * bb + 3]);
        const uint32_t u10 = pk2(sB0[4 * bb + 4], sB0[4 * bb + 5]);
        const uint32_t u11 = pk2(sB0[4 * bb + 6], sB0[4 * bb + 7]);
        const uint2v se0 =
            __builtin_amdgcn_permlane32_swap(u00, u10, false, false);
        const uint2v se1 =
            __builtin_amdgcn_permlane32_swap(u01, u11, false, false);
        uint32_t fr[4] = {se0.x, se1.x, se0.y, se1.y};
        pfB[e] = *reinterpret_cast<short8*>(fr);
      }
      {
        const uint32_t u00 = pk2(sB1[4 * bb + 0], sB1[4 * bb + 1]);
        const uint32_t u01 = pk2(sB1[4 * bb + 2], sB1[4 * bb + 3]);
        const uint32_t u10 = pk2(sB1[4 * bb + 4], sB1[4 * bb + 5]);
        const uint32_t u11 = pk2(sB1[4 * bb + 6], sB1[4 * bb + 7]);
        const uint2v se0 =
            __builtin_amdgcn_permlane32_swap(u00, u10, false, false);
        const uint2v se1 =
            __builtin_amdgcn_permlane32_swap(u01, u11, false, false);
        uint32_t fr[4] = {se0.x, se1.x, se0.y, se1.y};
        pfB[2 + e] = *reinterpret_cast<short8*>(fr);
      }
    }
  };

  // prologue: write tile 0, QK(0), stage(1), SM(0)
  *reinterpret_cast<uint4*>(lds + kpoW + wk0) = kst0;
  *reinterpret_cast<uint4*>(lds + kpoW + wk1) = kst1;
  *reinterpret_cast<uint4*>(lds + vW + wk0) = vst0;
  *reinterpret_cast<uint4*>(lds + vW + wk1) = vst1;
  __syncthreads();
  kst0 = *reinterpret_cast<const uint4*>(kgbase + 4096);
  kst1 = *reinterpret_cast<const uint4*>(kgbase + 4096 + 8);
  vst0 = *reinterpret_cast<const uint4*>(vgbase + 64);
  vst1 = *reinterpret_cast<const uint4*>(vgbase + 64 + 8);
  do_qk(kpoW);
  do_sm_pack();

  for (int t = 1; t < 16; ++t) {
    kpoW ^= 8192;
    vW = (vW == 32768) ? 16384 : vW + 8192;
    *reinterpret_cast<uint4*>(lds + kpoW + wk0) = kst0;
    *reinterpret_cast<uint4*>(lds + kpoW + wk1) = kst1;
    *reinterpret_cast<uint4*>(lds + vW + wk0) = vst0;
    *reinterpret_cast<uint4*>(lds + vW + wk1) = vst1;
    __syncthreads();

    // stage t+1 (wraps on last iter; data unused)
    const int tn = (t + 1) & 15;
    kst0 = *reinterpret_cast<const uint4*>(kgbase + tn * 4096);
    kst1 = *reinterpret_cast<const uint4*>(kgbase + tn * 4096 + 8);
    vst0 = *reinterpret_cast<const uint4*>(vgbase + tn * 64);
    vst1 = *reinterpret_cast<const uint4*>(vgbase + tn * 64 + 8);

    do_qk(kpoW);   // QK(t): MFMAs issue, results consumed later by SM
    do_pv(vR);     // PV(t-1): overlaps SM wait; o-order matches sequential
    vR = vW;
    do_sm_pack();  // SM(t) -> pf(t)
  }
  do_pv(vR);  // PV(15)

  // ---- cross-half reduce of l ----
  lA += __shfl_xor(lA, 32);
  lB += __shfl_xor(lB, 32);

  // ---- store partials ----
  if (lane < 32) {
    ML[(size_t)combo * S_LEN + qrowA] = float2{mA, lA};
    ML[(size_t)combo * S_LEN + qrowB] = float2{mB, lB};
  }
  ushort* obA = Opart + ((size_t)combo * S_LEN + qrowA) * HD;
  ushort* obB = Opart + ((size_t)combo * S_LEN + qrowB) * HD;
#pragma unroll
  for (int dt = 0; dt < 2; ++dt)
#pragma unroll
    for (int rq = 0; rq < 4; ++rq) {
      const int d = 32 * dt + 8 * rq + 4 * hh;
      uint2 pwA, pwB;
      pwA.x = pk2(oA[dt][4 * rq + 0], oA[dt][4 * rq + 1]);
      pwA.y = pk2(oA[dt][4 * rq + 2], oA[dt][4 * rq + 3]);
      pwB.x = pk2(oB[dt][4 * rq + 0], oB[dt][4 * rq + 1]);
      pwB.y = pk2(oB[dt][4 * rq + 2], oB[dt][4 * rq + 3]);
      *reinterpret_cast<uint2*>(obA + d) = pwA;
      *reinterpret_cast<uint2*>(obB + d) = pwB;
    }
}

extern "C" void kernel_launch(void* const* d_in, const int* in_sizes, int n_in,
                              void* d_out, int out_size, void* d_ws, size_t ws_size,
                              hipStream_t stream) {
  const float* x  = (const float*)d_in[0];
  const float* qp = (const float*)d_in[1];
  const float* kp = (const float*)d_in[2];
  const float* vp = (const float*)d_in[3];
  const float* pp = (const float*)d_in[4];
  float* out = (float*)d_out;

  unsigned char* ws = (unsigned char*)d_ws;
  ushort* xb    = (ushort*)(ws);                       // 4 MB
  ushort* qkvb  = (ushort*)(ws + ((size_t)4 << 20));   // 12 MB [3][8] planes
  ushort* wbT   = (ushort*)(ws + ((size_t)20 << 20));  // 1.5 MB
  ushort* ppT   = (ushort*)(ws + ((size_t)22 << 20));  // 0.5 MB
  ushort* opart = (ushort*)(ws + ((size_t)23 << 20));  // 16 MB [32][4096][64]
  float2* ml    = (float2*)(ws + ((size_t)39 << 20));  // 1 MB [32][4096]

  cast_x<<<dim3(1024), dim3(256), 0, stream>>>(x, xb);
  transpose_w<<<dim3(8, 8, 4), dim3(256), 0, stream>>>(qp, kp, vp, pp, wbT, ppT);
  gemm_bf16<0><<<dim3(32, 24), dim3(256), 0, stream>>>(xb, wbT, qkvb, nullptr);
  attn_mfma32<<<dim3(32, 16), dim3(256), 0, stream>>>(qkvb, opart, ml);
  gemm_bf16<2><<<dim3(32, 8), dim3(256), 0, stream>>>(opart, ppT, out, ml);
}